// Round 10
// baseline (246.865 us; speedup 1.0000x reference)
//
#include <hip/hip_runtime.h>

namespace {

constexpr int kB = 4096;
constexpr int kT = 256;
constexpr int kLags = 32;
constexpr int kH = 128;
constexpr int kSteps = 255;   // 32 warmup + 223 AR steps
constexpr int kOut = 224;     // kT - kLags
constexpr int kMT = 16;       // batch rows per block
constexpr int kThreads = 512; // 8 waves; wave w owns outcols 16w..16w+15
constexpr int kHS = 136;      // bf16 row stride: 272 B (measured-benign banks)
constexpr int kOS = 225;      // obuf row stride

typedef __attribute__((ext_vector_type(8))) short short8;
typedef __attribute__((ext_vector_type(4))) float f32x4;

struct __align__(16) SMem {
    unsigned short hhi[2][kMT][kHS];  // h high bf16, [buf][batch][col]
    unsigned short hlo[2][kMT][kHS];  // h low  bf16
    float x0T[kT][kMT];               // feature 0, transposed [t][batch]
    float x1wT[kLags][kMT];           // feature 1 warmup, transposed
    float obuf[kMT][kOS];             // ES output staging
};

__device__ __forceinline__ unsigned short bf16_rne(float f) {
    unsigned u = __builtin_bit_cast(unsigned, f);
    u += 0x7FFFu + ((u >> 16) & 1u);
    return (unsigned short)(u >> 16);
}
__device__ __forceinline__ float bf16_f32(unsigned short h) {
    unsigned u = ((unsigned)h) << 16;
    return __builtin_bit_cast(float, u);
}
// tanh(z) given z2 = 2*z (the *2 folded into weights/consts, exact)
__device__ __forceinline__ float tanh_from_2z(float z2) {
    float e = __expf(z2);
    return fmaf(-2.0f, __builtin_amdgcn_rcpf(e + 1.0f), 1.0f);
}
// RNE bf16 in TOP 16 bits (for v_perm byte [7,6]/[3,2] extraction)
__device__ __forceinline__ unsigned bf16_rne_hibits(float f) {
    unsigned u = __builtin_bit_cast(unsigned, f);
    return (u + (0x7FFFu + ((u >> 16) & 1u))) & 0xFFFF0000u;
}

__global__ __launch_bounds__(kThreads, 2)
void arx_rnn_es_kernel(const float* __restrict__ inputs,
                       const float* __restrict__ Wx,
                       const float* __restrict__ Wh,
                       const float* __restrict__ bias,
                       const float* __restrict__ Wd,
                       const float* __restrict__ bd,
                       const float* __restrict__ alpha,
                       float* __restrict__ out) {
    __shared__ SMem sm;
    const int tid  = threadIdx.x;
    const int b0   = blockIdx.x * kMT;
    const int lane = tid & 63;
    const int w    = tid >> 6;        // wave 0..7, owns outcols 16w..16w+15
    const int n    = lane & 15;       // batch row (B-frag col & C col)
    const int q    = lane >> 4;       // quad: C rows 4q..4q+3 (= outcols in tile)

    // ---------------- one-time staging ----------------
    for (int idx = tid; idx < kMT * kT; idx += kThreads) {
        const int mm = idx >> 8;
        const int t  = idx & 255;
        float2 v = ((const float2*)inputs)[(size_t)(b0 + mm) * kT + t];
        sm.x0T[t][mm] = v.x;
        if (t < kLags) sm.x1wT[t][mm] = v.y;
    }
    for (int idx = tid; idx < kMT * kHS; idx += kThreads) {
        ((unsigned short*)sm.hhi[0])[idx] = 0;
        ((unsigned short*)sm.hlo[0])[idx] = 0;
    }

    const float av  = fminf(fmaxf(alpha[0], 0.0f), 1.0f);
    const float bdv = bd[0];

    // ---- epilogue constants: this lane's outcols colE = 16w + 4q + r ----
    float sb2[4], swx0[4], swx1e[4], sbp[4];
#pragma unroll
    for (int r = 0; r < 4; ++r) {
        const int colE = w * 16 + q * 4 + r;
        const float bc = bias[colE];
        const float w0 = Wx[colE];
        const float w1 = Wx[kH + colE];
        sb2[r]   = 2.0f * bc;
        swx0[r]  = 2.0f * w0;
        swx1e[r] = 2.0f * w1;
        sbp[r]   = 2.0f * (bc + bdv * w1);   // folded bias for AR steps
    }
    __syncthreads();

    int p = 0;

    // ================= warmup: st = 0..31 (unfolded 2*Wh, real x1) =================
    {
        short8 whh[4], whl[4];
        {
            const int colw = w * 16 + n;
#pragma unroll
            for (int c = 0; c < 4; ++c) {
#pragma unroll
                for (int j = 0; j < 8; ++j) {
                    const int k = c * 32 + q * 8 + j;
                    float wv = 2.0f * Wh[(size_t)k * kH + colw];
                    unsigned short hi = bf16_rne(wv);
                    whh[c][j] = (short)hi;
                    whl[c][j] = (short)bf16_rne(wv - bf16_f32(hi));
                }
            }
        }

#pragma unroll 1
        for (int st = 0; st < kLags; ++st) {
            const float x0s = sm.x0T[st][n];
            const float x1s = sm.x1wT[st][n];

            // 3 parallel MFMA chains (4-deep each instead of one 12-deep)
            f32x4 A0 = *(const f32x4*)&sb2[0];
            f32x4 A1 = {0, 0, 0, 0};
            f32x4 A2 = {0, 0, 0, 0};
#pragma unroll
            for (int c = 0; c < 4; ++c) {
                short8 bh = *(const short8*)&sm.hhi[p][n][c * 32 + 8 * q];
                short8 bl = *(const short8*)&sm.hlo[p][n][c * 32 + 8 * q];
                A0 = __builtin_amdgcn_mfma_f32_16x16x32_bf16(whh[c], bh, A0, 0, 0, 0);
                A1 = __builtin_amdgcn_mfma_f32_16x16x32_bf16(whl[c], bh, A1, 0, 0, 0);
                A2 = __builtin_amdgcn_mfma_f32_16x16x32_bf16(whh[c], bl, A2, 0, 0, 0);
            }
            f32x4 A = (A0 + A1) + A2;

            unsigned rb[4], db[4];
#pragma unroll
            for (int r = 0; r < 4; ++r) {
                float z2 = A[r] + x0s * swx0[r] + x1s * swx1e[r];
                float hf = tanh_from_2z(z2);
                rb[r] = bf16_rne_hibits(hf);
                float d = hf - __builtin_bit_cast(float, rb[r]);
                db[r] = bf16_rne_hibits(d);   // RNE lo (R3 numerics)
            }
            uint2 uh, ul;
            uh.x = __builtin_amdgcn_perm(rb[1], rb[0], 0x07060302u);
            uh.y = __builtin_amdgcn_perm(rb[3], rb[2], 0x07060302u);
            ul.x = __builtin_amdgcn_perm(db[1], db[0], 0x07060302u);
            ul.y = __builtin_amdgcn_perm(db[3], db[2], 0x07060302u);
            const int wcol = w * 16 + q * 4;
            *(uint2*)&sm.hhi[1 - p][n][wcol] = uh;
            *(uint2*)&sm.hlo[1 - p][n][wcol] = ul;

            __syncthreads();
            p ^= 1;
        }
    }

    // ---- folded AR weights 2*(Wh + Wd*wx1^T) and Wd-replicated pred frag ----
    short8 fhh[4], fhl[4], dh[4];
    {
        const int colw = w * 16 + n;
        const float wx1w = Wx[kH + colw];
#pragma unroll
        for (int c = 0; c < 4; ++c) {
#pragma unroll
            for (int j = 0; j < 8; ++j) {
                const int k = c * 32 + q * 8 + j;
                float wv = 2.0f * fmaf(Wd[k], wx1w, Wh[(size_t)k * kH + colw]);
                unsigned short hi = bf16_rne(wv);
                fhh[c][j] = (short)hi;
                fhl[c][j] = (short)bf16_rne(wv - bf16_f32(hi));
                dh[c][j]  = (short)bf16_rne(Wd[k]);  // k-only: same for all rows
            }
        }
    }

    float es = 0.0f;                      // wave 0, q==0 lanes: es for batch row n
    f32x4 pprev0 = {0, 0, 0, 0};          // wave 0: pred partials from previous
    f32x4 pprev1 = {0, 0, 0, 0};          //   iteration, carried in registers

    // ================= AR: st = 32..254 =================
    // wave 0 computes pred partials via MFMA each step; ES consumes them one
    // iteration LATER (register-deferred — result has a full iteration of slack)
#pragma unroll 1
    for (int st = kLags; st < kSteps; ++st) {
        const float x0s = sm.x0T[st][n];

        // deferred ES: consume pred computed last iteration (post-barrier slack)
        if (w == 0 && q == 0 && st > kLags) {
            float pv = pprev0[0] + pprev1[0] + bdv;
            es = (st == kLags + 1) ? pv : fmaf(av, pv - es, es);
            sm.obuf[n][st - kLags - 1] = es;
        }

        f32x4 A0 = *(const f32x4*)&sbp[0];
        f32x4 A1 = {0, 0, 0, 0};
        f32x4 A2 = {0, 0, 0, 0};
        f32x4 P0 = {0, 0, 0, 0};
        f32x4 P1 = {0, 0, 0, 0};
#pragma unroll
        for (int c = 0; c < 4; ++c) {
            short8 bh = *(const short8*)&sm.hhi[p][n][c * 32 + 8 * q];
            short8 bl = *(const short8*)&sm.hlo[p][n][c * 32 + 8 * q];
            A0 = __builtin_amdgcn_mfma_f32_16x16x32_bf16(fhh[c], bh, A0, 0, 0, 0);
            A1 = __builtin_amdgcn_mfma_f32_16x16x32_bf16(fhl[c], bh, A1, 0, 0, 0);
            A2 = __builtin_amdgcn_mfma_f32_16x16x32_bf16(fhh[c], bl, A2, 0, 0, 0);
            if (w == 0) {   // pred partials of h entering this step
                P0 = __builtin_amdgcn_mfma_f32_16x16x32_bf16(dh[c], bh, P0, 0, 0, 0);
                P1 = __builtin_amdgcn_mfma_f32_16x16x32_bf16(dh[c], bl, P1, 0, 0, 0);
            }
        }
        pprev0 = P0;
        pprev1 = P1;

        f32x4 A = (A0 + A1) + A2;
        unsigned rb[4], db[4];
#pragma unroll
        for (int r = 0; r < 4; ++r) {
            float z2 = A[r] + x0s * swx0[r];
            float hf = tanh_from_2z(z2);
            rb[r] = bf16_rne_hibits(hf);
            float d = hf - __builtin_bit_cast(float, rb[r]);
            db[r] = bf16_rne_hibits(d);
        }
        uint2 uh, ul;
        uh.x = __builtin_amdgcn_perm(rb[1], rb[0], 0x07060302u);
        uh.y = __builtin_amdgcn_perm(rb[3], rb[2], 0x07060302u);
        ul.x = __builtin_amdgcn_perm(db[1], db[0], 0x07060302u);
        ul.y = __builtin_amdgcn_perm(db[3], db[2], 0x07060302u);
        const int wcol = w * 16 + q * 4;
        *(uint2*)&sm.hhi[1 - p][n][wcol] = uh;
        *(uint2*)&sm.hlo[1 - p][n][wcol] = ul;

        __syncthreads();
        p ^= 1;
    }

    // ================= tail: col 222 (pprev = pred_222) and col 223 (pred h_255) ===
    if (w == 0) {
        f32x4 P0 = {0, 0, 0, 0};
        f32x4 P1 = {0, 0, 0, 0};
#pragma unroll
        for (int c = 0; c < 4; ++c) {
            short8 bh = *(const short8*)&sm.hhi[p][n][c * 32 + 8 * q];
            short8 bl = *(const short8*)&sm.hlo[p][n][c * 32 + 8 * q];
            P0 = __builtin_amdgcn_mfma_f32_16x16x32_bf16(dh[c], bh, P0, 0, 0, 0);
            P1 = __builtin_amdgcn_mfma_f32_16x16x32_bf16(dh[c], bl, P1, 0, 0, 0);
        }
        if (q == 0) {
            float pv = pprev0[0] + pprev1[0] + bdv;   // pred_222 (computed at st=254)
            es = fmaf(av, pv - es, es);
            sm.obuf[n][kOut - 2] = es;
            float pv2 = P0[0] + P1[0] + bdv;          // pred_223 (from h_255)
            es = fmaf(av, pv2 - es, es);
            sm.obuf[n][kOut - 1] = es;
        }
    }

    // ================= flush ES staging buffer to HBM (coalesced) =================
    __syncthreads();
    for (int idx = tid; idx < kMT * kOut; idx += kThreads) {
        const int mm = idx / kOut;
        const int t  = idx - mm * kOut;
        out[(size_t)(b0 + mm) * kOut + t] = sm.obuf[mm][t];
    }
}

}  // namespace

extern "C" void kernel_launch(void* const* d_in, const int* in_sizes, int n_in,
                              void* d_out, int out_size, void* d_ws, size_t ws_size,
                              hipStream_t stream) {
    const float* inputs = (const float*)d_in[0];
    const float* Wx     = (const float*)d_in[1];
    const float* Wh     = (const float*)d_in[2];
    const float* bias   = (const float*)d_in[3];
    const float* Wd     = (const float*)d_in[4];
    const float* bd     = (const float*)d_in[5];
    const float* alpha  = (const float*)d_in[6];
    // d_in[7] = lags (compile-time constant 32 here)

    arx_rnn_es_kernel<<<kB / kMT, kThreads, 0, stream>>>(
        inputs, Wx, Wh, bias, Wd, bd, alpha, (float*)d_out);
}

// Round 11
// 205.976 us; speedup vs baseline: 1.1985x; 1.1985x over previous
//
#include <hip/hip_runtime.h>

namespace {

constexpr int kB = 4096;
constexpr int kT = 256;
constexpr int kLags = 32;
constexpr int kH = 128;
constexpr int kSteps = 255;   // 32 warmup + 223 AR steps
constexpr int kOut = 224;     // kT - kLags
constexpr int kMT = 16;       // batch rows per block
constexpr int kThreads = 512; // 8 waves; wave w owns outcols 16w..16w+15
constexpr int kHS = 136;      // bf16 row stride: 272 B (measured-benign banks)
constexpr int kOS = 225;      // obuf row stride

// z-path pre-scale: 2 * log2(e). tanh(z) = 1 - 2/(exp2(2*log2e*z)+1),
// so v_exp_f32 (=exp2) needs no per-element 1/ln2 multiply.
constexpr float kZS = 2.8853900817779268f;

typedef __attribute__((ext_vector_type(8))) short short8;
typedef __attribute__((ext_vector_type(4))) float f32x4;

struct __align__(16) SMem {
    unsigned short hhi[2][kMT][kHS];  // h high bf16, [buf][batch][col]
    unsigned short hlo[2][kMT][kHS];  // h low  bf16
    float x0T[kT][kMT];               // feature 0, transposed [t][batch]
    float x1wT[kLags][kMT];           // feature 1 warmup, transposed
    float obuf[kMT][kOS];             // ES output staging
};

__device__ __forceinline__ unsigned short bf16_rne(float f) {
    unsigned u = __builtin_bit_cast(unsigned, f);
    u += 0x7FFFu + ((u >> 16) & 1u);
    return (unsigned short)(u >> 16);
}
__device__ __forceinline__ float bf16_f32(unsigned short h) {
    unsigned u = ((unsigned)h) << 16;
    return __builtin_bit_cast(float, u);
}
// tanh(z) given zs = 2*log2(e)*z  (scale folded into weights, exact math)
__device__ __forceinline__ float tanh_from_zs(float zs) {
    float e = __builtin_amdgcn_exp2f(zs);
    return fmaf(-2.0f, __builtin_amdgcn_rcpf(e + 1.0f), 1.0f);
}
// RNE bf16 in TOP 16 bits (for v_perm byte [7,6]/[3,2] extraction)
__device__ __forceinline__ unsigned bf16_rne_hibits(float f) {
    unsigned u = __builtin_bit_cast(unsigned, f);
    return (u + (0x7FFFu + ((u >> 16) & 1u))) & 0xFFFF0000u;
}

__global__ __launch_bounds__(kThreads, 2)
void arx_rnn_es_kernel(const float* __restrict__ inputs,
                       const float* __restrict__ Wx,
                       const float* __restrict__ Wh,
                       const float* __restrict__ bias,
                       const float* __restrict__ Wd,
                       const float* __restrict__ bd,
                       const float* __restrict__ alpha,
                       float* __restrict__ out) {
    __shared__ SMem sm;
    const int tid  = threadIdx.x;
    const int b0   = blockIdx.x * kMT;
    const int lane = tid & 63;
    const int w    = tid >> 6;        // wave 0..7, owns outcols 16w..16w+15
    const int n    = lane & 15;       // batch row (B-frag col & C col)
    const int q    = lane >> 4;       // quad: C rows 4q..4q+3 (= outcols in tile)

    // ---------------- one-time staging ----------------
    for (int idx = tid; idx < kMT * kT; idx += kThreads) {
        const int mm = idx >> 8;
        const int t  = idx & 255;
        float2 v = ((const float2*)inputs)[(size_t)(b0 + mm) * kT + t];
        sm.x0T[t][mm] = v.x;
        if (t < kLags) sm.x1wT[t][mm] = v.y;
    }
    for (int idx = tid; idx < kMT * kHS; idx += kThreads) {
        ((unsigned short*)sm.hhi[0])[idx] = 0;
        ((unsigned short*)sm.hlo[0])[idx] = 0;
    }

    const float av  = fminf(fmaxf(alpha[0], 0.0f), 1.0f);
    const float bdv = bd[0];

    // ---- epilogue constants (all z-path consts pre-scaled by kZS) ----
    float sb2[4], swx0[4], swx1e[4], sbp[4];
#pragma unroll
    for (int r = 0; r < 4; ++r) {
        const int colE = w * 16 + q * 4 + r;
        const float bc = bias[colE];
        const float w0 = Wx[colE];
        const float w1 = Wx[kH + colE];
        sb2[r]   = kZS * bc;
        swx0[r]  = kZS * w0;
        swx1e[r] = kZS * w1;
        sbp[r]   = kZS * (bc + bdv * w1);   // folded bias for AR steps
    }
    __syncthreads();

    int p = 0;

    // ================= warmup: st = 0..31 (unfolded kZS*Wh, real x1) ===============
    {
        short8 whh[4], whl[4];
        {
            const int colw = w * 16 + n;
#pragma unroll
            for (int c = 0; c < 4; ++c) {
#pragma unroll
                for (int j = 0; j < 8; ++j) {
                    const int k = c * 32 + q * 8 + j;
                    float wv = kZS * Wh[(size_t)k * kH + colw];
                    unsigned short hi = bf16_rne(wv);
                    whh[c][j] = (short)hi;
                    whl[c][j] = (short)bf16_rne(wv - bf16_f32(hi));
                }
            }
        }

#pragma unroll 1
        for (int st = 0; st < kLags; ++st) {
            const float x0s = sm.x0T[st][n];
            const float x1s = sm.x1wT[st][n];

            // hoist all 8 h-reads ahead of the MFMA sequence (feed DS pipe early)
            short8 bh[4], bl[4];
#pragma unroll
            for (int c = 0; c < 4; ++c) {
                bh[c] = *(const short8*)&sm.hhi[p][n][c * 32 + 8 * q];
                bl[c] = *(const short8*)&sm.hlo[p][n][c * 32 + 8 * q];
            }

            f32x4 A = *(const f32x4*)&sb2[0];   // bias preloaded into acc
#pragma unroll
            for (int c = 0; c < 4; ++c) {
                A = __builtin_amdgcn_mfma_f32_16x16x32_bf16(whh[c], bh[c], A, 0, 0, 0);
                A = __builtin_amdgcn_mfma_f32_16x16x32_bf16(whl[c], bh[c], A, 0, 0, 0);
                A = __builtin_amdgcn_mfma_f32_16x16x32_bf16(whh[c], bl[c], A, 0, 0, 0);
            }

            unsigned rb[4], db[4];
#pragma unroll
            for (int r = 0; r < 4; ++r) {
                float zs = A[r] + x0s * swx0[r] + x1s * swx1e[r];
                float hf = tanh_from_zs(zs);
                rb[r] = bf16_rne_hibits(hf);
                float d = hf - __builtin_bit_cast(float, rb[r]);
                db[r] = __builtin_bit_cast(unsigned, d);   // trunc lo (top 16 bits)
            }
            uint2 uh, ul;
            uh.x = __builtin_amdgcn_perm(rb[1], rb[0], 0x07060302u);
            uh.y = __builtin_amdgcn_perm(rb[3], rb[2], 0x07060302u);
            ul.x = __builtin_amdgcn_perm(db[1], db[0], 0x07060302u);
            ul.y = __builtin_amdgcn_perm(db[3], db[2], 0x07060302u);
            const int wcol = w * 16 + q * 4;
            *(uint2*)&sm.hhi[1 - p][n][wcol] = uh;
            *(uint2*)&sm.hlo[1 - p][n][wcol] = ul;

            __syncthreads();
            p ^= 1;
        }
    }

    // ---- folded AR weights kZS*(Wh + Wd*wx1^T) and Wd-replicated pred frag ----
    // dh (pred path) is NOT kZS-scaled: pred = h.Wd + bd directly.
    short8 fhh[4], fhl[4], dh[4];
    {
        const int colw = w * 16 + n;
        const float wx1w = Wx[kH + colw];
#pragma unroll
        for (int c = 0; c < 4; ++c) {
#pragma unroll
            for (int j = 0; j < 8; ++j) {
                const int k = c * 32 + q * 8 + j;
                float wv = kZS * fmaf(Wd[k], wx1w, Wh[(size_t)k * kH + colw]);
                unsigned short hi = bf16_rne(wv);
                fhh[c][j] = (short)hi;
                fhl[c][j] = (short)bf16_rne(wv - bf16_f32(hi));
                dh[c][j]  = (short)bf16_rne(Wd[k]);  // k-only: same for all rows
            }
        }
    }

    float es = 0.0f;   // wave 0, q==0 lanes: es for batch row n

    // ================= AR: st = 32..254 (pred folded; output-pred from h_hi only) ==
#pragma unroll 1
    for (int st = kLags; st < kSteps; ++st) {
        const float x0s = sm.x0T[st][n];

        short8 bh[4], bl[4];
#pragma unroll
        for (int c = 0; c < 4; ++c) {
            bh[c] = *(const short8*)&sm.hhi[p][n][c * 32 + 8 * q];
            bl[c] = *(const short8*)&sm.hlo[p][n][c * 32 + 8 * q];
        }

        f32x4 A = *(const f32x4*)&sbp[0];
        f32x4 P = {0, 0, 0, 0};
#pragma unroll
        for (int c = 0; c < 4; ++c) {
            A = __builtin_amdgcn_mfma_f32_16x16x32_bf16(fhh[c], bh[c], A, 0, 0, 0);
            A = __builtin_amdgcn_mfma_f32_16x16x32_bf16(fhl[c], bh[c], A, 0, 0, 0);
            A = __builtin_amdgcn_mfma_f32_16x16x32_bf16(fhh[c], bl[c], A, 0, 0, 0);
            if (w == 0)   // output-pred partial: h_hi only (h_lo term ~3e-4, ES-smoothed)
                P = __builtin_amdgcn_mfma_f32_16x16x32_bf16(dh[c], bh[c], P, 0, 0, 0);
        }

        // ES stream -> LDS staging; wave 0, q==0 lanes own batch row n
        if (w == 0 && q == 0) {
            float pv = P[0] + bdv;
            es = (st == kLags) ? pv : fmaf(av, pv - es, es);
            sm.obuf[n][st - kLags] = es;
        }

        unsigned rb[4], db[4];
#pragma unroll
        for (int r = 0; r < 4; ++r) {
            float zs = A[r] + x0s * swx0[r];
            float hf = tanh_from_zs(zs);
            rb[r] = bf16_rne_hibits(hf);
            float d = hf - __builtin_bit_cast(float, rb[r]);
            db[r] = __builtin_bit_cast(unsigned, d);
        }
        uint2 uh, ul;
        uh.x = __builtin_amdgcn_perm(rb[1], rb[0], 0x07060302u);
        uh.y = __builtin_amdgcn_perm(rb[3], rb[2], 0x07060302u);
        ul.x = __builtin_amdgcn_perm(db[1], db[0], 0x07060302u);
        ul.y = __builtin_amdgcn_perm(db[3], db[2], 0x07060302u);
        const int wcol = w * 16 + q * 4;
        *(uint2*)&sm.hhi[1 - p][n][wcol] = uh;
        *(uint2*)&sm.hlo[1 - p][n][wcol] = ul;

        __syncthreads();
        p ^= 1;
    }

    // ================= tail: pred from h_255 (hi) -> es -> col 223 =================
    if (w == 0) {
        f32x4 P = {0, 0, 0, 0};
#pragma unroll
        for (int c = 0; c < 4; ++c) {
            short8 bh = *(const short8*)&sm.hhi[p][n][c * 32 + 8 * q];
            P = __builtin_amdgcn_mfma_f32_16x16x32_bf16(dh[c], bh, P, 0, 0, 0);
        }
        if (q == 0) {
            float pv = P[0] + bdv;
            es = fmaf(av, pv - es, es);
            sm.obuf[n][kOut - 1] = es;
        }
    }

    // ================= flush ES staging buffer to HBM (coalesced) =================
    __syncthreads();
    for (int idx = tid; idx < kMT * kOut; idx += kThreads) {
        const int mm = idx / kOut;
        const int t  = idx - mm * kOut;
        out[(size_t)(b0 + mm) * kOut + t] = sm.obuf[mm][t];
    }
}

}  // namespace

extern "C" void kernel_launch(void* const* d_in, const int* in_sizes, int n_in,
                              void* d_out, int out_size, void* d_ws, size_t ws_size,
                              hipStream_t stream) {
    const float* inputs = (const float*)d_in[0];
    const float* Wx     = (const float*)d_in[1];
    const float* Wh     = (const float*)d_in[2];
    const float* bias   = (const float*)d_in[3];
    const float* Wd     = (const float*)d_in[4];
    const float* bd     = (const float*)d_in[5];
    const float* alpha  = (const float*)d_in[6];
    // d_in[7] = lags (compile-time constant 32 here)

    arx_rnn_es_kernel<<<kB / kMT, kThreads, 0, stream>>>(
        inputs, Wx, Wh, bias, Wd, bd, alpha, (float*)d_out);
}